// Round 14
// baseline (136.347 us; speedup 1.0000x reference)
//
#include <hip/hip_runtime.h>
#include <hip/hip_fp16.h>

// Ultimus: out = x + softmax((x@Kw+Kb)@(x@Qw+Qb)^T / sqrt(8)) @ (x@Vw+Vb) @ Zw + Zb
// N=8192, D_IN=48, D_ATTN=8, fp32 in/out.
//
// R14: plain-f32 hot math. CDNA vector FP16 = FP32 FLOP rate (v_pk_fma_f16
// is 4 cyc vs v_fma_f32 2 cyc), so R11-R13's packed-f16 math was half-rate —
// that was the ~35 us wall. f16 is now storage-only:
//  - LDS tile: 32 B/j (q8+v8 halfs), 2 uniform ds_read_b128 per j (broadcast)
//  - 16 cvt/j amortized over 4 rows/lane; all FMAs are v_fma_f32 (full rate)
//  - R13 skeleton, 256-thr blocks: 4 waves share tile + chunk, disjoint rows
//    => no merge, one barrier total; c-major f16 partials; finish sums 128.
//  - Bound-softmax (Cauchy-Schwarz) fixed exponent shift => partials add.
//
// ws layout (floats):
//   [0, 65536)        Xksf32[8192][8] f32 k rows, pre-scaled by log2e/sqrt(8)
//   [65536, 131072)   QVf16: per j, 8 dwords = q[j] 8 halfs | v[j] 8 halfs
//   [131072, 131328)  bmax[256] per-proj-block max ||q||^2 (plain store)
//   [131328, ...)     partH[nch][9][8192] f16 partials, c-major

#define QV_OFF   65536
#define BMAX_OFF 131072
#define PART_OFF 131328

typedef _Float16 hv2 __attribute__((ext_vector_type(2)));
union HVU { unsigned u; hv2 v; };

static __device__ __forceinline__ unsigned pku(float a, float b) {
    auto t = __builtin_amdgcn_cvt_pkrtz(a, b);
    union { decltype(t) x; unsigned u; } c; c.x = t; return c.u;
}
static __device__ __forceinline__ hv2 asV(unsigned u) { HVU t; t.u = u; return t.v; }

__global__ __launch_bounds__(256) void proj_kernel(
    const float* __restrict__ x,
    const float* __restrict__ Kw, const float* __restrict__ Kb,
    const float* __restrict__ Qw, const float* __restrict__ Qb,
    const float* __restrict__ Vw, const float* __restrict__ Vb,
    float* __restrict__ Xksf32, unsigned* __restrict__ QV,
    float* __restrict__ bmax)
{
    __shared__ float xs[32 * 49];     // +1 pad
    __shared__ float wAll[3 * 388];   // stride 388 (mod 32 = 4) spreads 3 mats
    __shared__ float bs[24];
    __shared__ float outv[32][25];    // 24 cols + pad
    const int tid = threadIdx.x;
    const int r0 = blockIdx.x * 32;

    for (int i = tid; i < 1536; i += 256) {
        int r = i / 48, c = i - r * 48;
        xs[r * 49 + c] = x[r0 * 48 + i];
    }
    for (int i = tid; i < 384; i += 256) {
        wAll[i]       = Kw[i];
        wAll[388 + i] = Qw[i];
        wAll[776 + i] = Vw[i];
    }
    if (tid < 8)       bs[tid] = Kb[tid];
    else if (tid < 16) bs[tid] = Qb[tid - 8];
    else if (tid < 24) bs[tid] = Vb[tid - 16];
    __syncthreads();

    const int rl = tid >> 3;
    const int g  = tid & 7;
    const int c0 = 3 * g;
    const float* xr = &xs[rl * 49];
    const float* w0 = &wAll[((c0 + 0) >> 3) * 388 + ((c0 + 0) & 7)];
    const float* w1 = &wAll[((c0 + 1) >> 3) * 388 + ((c0 + 1) & 7)];
    const float* w2 = &wAll[((c0 + 2) >> 3) * 388 + ((c0 + 2) & 7)];
    float a0 = bs[c0], a1 = bs[c0 + 1], a2 = bs[c0 + 2];
    #pragma unroll
    for (int k = 0; k < 48; k++) {
        const float xv = xr[k];
        a0 = fmaf(xv, w0[k * 8], a0);
        a1 = fmaf(xv, w1[k * 8], a1);
        a2 = fmaf(xv, w2[k * 8], a2);
    }
    outv[rl][c0] = a0; outv[rl][c0 + 1] = a1; outv[rl][c0 + 2] = a2;
    __syncthreads();

    const float kscale = 0.51008732149f;  // (1/sqrt(8)) * log2(e)
    {   // K rows f32, pre-scaled: thread = (row r, col c), coalesced
        const int r = tid >> 3, c = tid & 7;
        Xksf32[(r0 + r) * 8 + c] = outv[r][c] * kscale;
    }
    {   // QV f16: per j 8 dwords (q pairs then v pairs); thread = (j, d)
        const int j = tid >> 3, d = tid & 7;
        const int base = (d < 4) ? (8 + 2 * d) : (16 + 2 * (d - 4));
        QV[(r0 + j) * 8 + d] = pku(outv[j][base], outv[j][base + 1]);
    }
    if (tid >= 192 && tid < 224) {        // block-max ||q||^2 (fp32)
        const int r = tid - 192;
        float n2 = 0.f;
        #pragma unroll
        for (int c = 0; c < 8; c++) n2 = fmaf(outv[r][8 + c], outv[r][8 + c], n2);
        #pragma unroll
        for (int off = 16; off > 0; off >>= 1)
            n2 = fmaxf(n2, __shfl_xor(n2, off, 64));
        if (r == 0) bmax[blockIdx.x] = n2;
    }
}

// grid = 8 row-groups (1024 rows: 4 waves x 64 lanes x 4 rows/lane) x nch.
// All waves share one 64-j tile (2 KB) and the same chunk; rows disjoint.
__global__ __launch_bounds__(256) void attn_kernel(
    const float* __restrict__ Xksf32, const unsigned* __restrict__ QV,
    const float* __restrict__ bmax,
    __half* __restrict__ partH, int C)
{
    __shared__ uint4 tile4[256];       // up to 128 j x 32 B
    const int tid  = threadIdx.x;
    const int lane = tid & 63;
    const int wv   = tid >> 6;
    const int g    = blockIdx.x & 7;
    const int ch   = blockIdx.x >> 3;

    // stage chunk tile: C j's x 2 uint4 (coalesced), single barrier below
    for (int i = tid; i < C * 2; i += 256)
        tile4[i] = ((const uint4*)QV)[(size_t)ch * C * 2 + i];

    // qmax2 = max over 256 per-proj-block maxima
    float m = fmaxf(fmaxf(bmax[lane], bmax[64 + lane]),
                    fmaxf(bmax[128 + lane], bmax[192 + lane]));
    #pragma unroll
    for (int off = 32; off > 0; off >>= 1)
        m = fmaxf(m, __shfl_xor(m, off, 64));
    const float qmax2 = m;

    const int rbase = g * 1024 + wv * 256 + lane;   // rows: rbase + 64k
    float kf[4][8], sinit[4], l[4], acc[4][8];
    const float4* Xk4 = (const float4*)Xksf32;
    #pragma unroll
    for (int k = 0; k < 4; k++) {
        const int row = rbase + 64 * k;             // coalesced per k
        const float4 ka = Xk4[row * 2], kb = Xk4[row * 2 + 1];
        kf[k][0] = ka.x; kf[k][1] = ka.y; kf[k][2] = ka.z; kf[k][3] = ka.w;
        kf[k][4] = kb.x; kf[k][5] = kb.y; kf[k][6] = kb.z; kf[k][7] = kb.w;
        float kn2 = 0.f;
        #pragma unroll
        for (int c = 0; c < 8; c++) kn2 = fmaf(kf[k][c], kf[k][c], kn2);
        sinit[k] = -sqrtf(kn2 * qmax2);  // s <= -sinit: p in (0,~1]
        l[k] = 0.f;
        #pragma unroll
        for (int c = 0; c < 8; c++) acc[k][c] = 0.f;
    }

    __syncthreads();                   // tile ready; no further barriers

    #pragma unroll 2
    for (int j = 0; j < C; j++) {
        // wave-uniform ds_read_b128 x2: broadcast, in-order, pipelined
        const uint4 qd = tile4[j * 2];
        const uint4 vd = tile4[j * 2 + 1];
        float qf[8], vf[8];
        { hv2 h = asV(qd.x); qf[0] = (float)h.x; qf[1] = (float)h.y; }
        { hv2 h = asV(qd.y); qf[2] = (float)h.x; qf[3] = (float)h.y; }
        { hv2 h = asV(qd.z); qf[4] = (float)h.x; qf[5] = (float)h.y; }
        { hv2 h = asV(qd.w); qf[6] = (float)h.x; qf[7] = (float)h.y; }
        { hv2 h = asV(vd.x); vf[0] = (float)h.x; vf[1] = (float)h.y; }
        { hv2 h = asV(vd.y); vf[2] = (float)h.x; vf[3] = (float)h.y; }
        { hv2 h = asV(vd.z); vf[4] = (float)h.x; vf[5] = (float)h.y; }
        { hv2 h = asV(vd.w); vf[6] = (float)h.x; vf[7] = (float)h.y; }
        #pragma unroll
        for (int k = 0; k < 4; k++) {
            float s = sinit[k];
            s = fmaf(kf[k][0], qf[0], s); s = fmaf(kf[k][1], qf[1], s);
            s = fmaf(kf[k][2], qf[2], s); s = fmaf(kf[k][3], qf[3], s);
            s = fmaf(kf[k][4], qf[4], s); s = fmaf(kf[k][5], qf[5], s);
            s = fmaf(kf[k][6], qf[6], s); s = fmaf(kf[k][7], qf[7], s);
            const float p = __builtin_amdgcn_exp2f(s);
            l[k] += p;
            acc[k][0] = fmaf(p, vf[0], acc[k][0]);
            acc[k][1] = fmaf(p, vf[1], acc[k][1]);
            acc[k][2] = fmaf(p, vf[2], acc[k][2]);
            acc[k][3] = fmaf(p, vf[3], acc[k][3]);
            acc[k][4] = fmaf(p, vf[4], acc[k][4]);
            acc[k][5] = fmaf(p, vf[5], acc[k][5]);
            acc[k][6] = fmaf(p, vf[6], acc[k][6]);
            acc[k][7] = fmaf(p, vf[7], acc[k][7]);
        }
    }

    // c-major f16 partial store: lanes = consecutive rows (coalesced)
    #pragma unroll
    for (int k = 0; k < 4; k++) {
        const int row = rbase + 64 * k;
        #pragma unroll
        for (int c = 0; c < 8; c++)
            partH[((size_t)(ch * 9 + c) << 13) + row] = __float2half_rn(acc[k][c]);
        partH[((size_t)(ch * 9 + 8) << 13) + row] = __float2half_rn(l[k]);
    }
}

// grid = 128 blocks x 64 rows; thread (r = tid&63, slice-group s = tid>>6)
__global__ __launch_bounds__(256) void finish_kernel(
    const float* __restrict__ x,
    const float* __restrict__ Zw, const float* __restrict__ Zb,
    const __half* __restrict__ partH, float* __restrict__ out, int nch)
{
    __shared__ float red[4][64][10];
    __shared__ float Zs[64][9];
    __shared__ float zw_s[384];
    __shared__ float zb_s[48];
    const int tid = threadIdx.x;
    const int r0 = blockIdx.x * 64;

    for (int i = tid; i < 384; i += 256) zw_s[i] = Zw[i];
    if (tid < 48) zb_s[tid] = Zb[tid];

    const int r = tid & 63, s = tid >> 6;
    const int row = r0 + r;
    const int cps = nch >> 2;
    float a[9];
    #pragma unroll
    for (int c = 0; c < 9; c++) a[c] = 0.f;
    for (int i = 0; i < cps; i++) {
        const int ch = s * cps + i;
        const __half* p = partH + ((size_t)(ch * 9) << 13) + row;
        #pragma unroll
        for (int c = 0; c < 9; c++) a[c] += __half2float(p[(size_t)c << 13]);
    }
    #pragma unroll
    for (int c = 0; c < 9; c++) red[s][r][c] = a[c];
    __syncthreads();
    if (tid < 64) {
        float b[9];
        #pragma unroll
        for (int c = 0; c < 9; c++)
            b[c] = red[0][tid][c] + red[1][tid][c] + red[2][tid][c] + red[3][tid][c];
        const float inv = 1.0f / b[8];
        #pragma unroll
        for (int c = 0; c < 8; c++) Zs[tid][c] = b[c] * inv;
    }
    __syncthreads();

    for (int e = tid; e < 64 * 48; e += 256) {
        const int rr = e / 48, c = e - rr * 48;
        float o = x[r0 * 48 + e] + zb_s[c];
        #pragma unroll
        for (int k = 0; k < 8; k++) o = fmaf(Zs[rr][k], zw_s[k * 48 + c], o);
        out[r0 * 48 + e] = o;
    }
}

extern "C" void kernel_launch(void* const* d_in, const int* in_sizes, int n_in,
                              void* d_out, int out_size, void* d_ws, size_t ws_size,
                              hipStream_t stream) {
    const float* x  = (const float*)d_in[0];
    const float* Kw = (const float*)d_in[1];
    const float* Kb = (const float*)d_in[2];
    const float* Qw = (const float*)d_in[3];
    const float* Qb = (const float*)d_in[4];
    const float* Vw = (const float*)d_in[5];
    const float* Vb = (const float*)d_in[6];
    const float* Zw = (const float*)d_in[7];
    const float* Zb = (const float*)d_in[8];
    float* out = (float*)d_out;

    float* ws = (float*)d_ws;
    float* Xksf32 = ws;
    unsigned* QV  = (unsigned*)(ws + QV_OFF);
    float* bmax   = ws + BMAX_OFF;
    __half* partH = (__half*)(ws + PART_OFF);

    // largest chunk count whose f16 partials fit (tile cap: C <= 128 j)
    int nch = 128;
    while (nch > 64 &&
           (size_t)PART_OFF * 4 + (size_t)nch * 9 * 8192 * 2 > ws_size) nch >>= 1;
    const int C = 8192 / nch;   // j's per chunk (64 when nch=128)

    proj_kernel<<<256, 256, 0, stream>>>(x, Kw, Kb, Qw, Qb, Vw, Vb,
                                         Xksf32, QV, bmax);
    attn_kernel<<<8 * nch, 256, 0, stream>>>(Xksf32, QV, bmax, partH, C);
    finish_kernel<<<128, 256, 0, stream>>>(x, Zw, Zb, partH, out, nch);
}

// Round 15
// 130.076 us; speedup vs baseline: 1.0482x; 1.0482x over previous
//
#include <hip/hip_runtime.h>
#include <hip/hip_fp16.h>

// Ultimus: out = x + softmax((x@Kw+Kb)@(x@Qw+Qb)^T / sqrt(8)) @ (x@Vw+Vb) @ Zw + Zb
// N=8192, D_IN=48, D_ATTN=8, fp32 in/out.
//
// R15 = R14 minus the in-loop cvt tax. R14 counters: attn 44 us, VALUBusy
// 66% => 29 us VALU-busy vs 19 us model; excess = 16x v_cvt_f32_f16 per
// wave-j (tile was f16, each wave converted independently). Now the f16->f32
// conversion happens ONCE at staging (block-cooperative, 512 dwords -> 2 cvt
// per thread), and the hot loop is pure: 4 uniform ds_read_b128 (f32 tile,
// LDS broadcast) + 72 v_fma_f32 + 4 v_exp_f32 per wave-j. Vector-pipe floor
// = 14.5 (fma) + 3.4 (exp) us; DS 20.5 us/CU overlaps.
//
// ws layout (floats):
//   [0, 65536)        Xksf32[8192][8] f32 k rows, pre-scaled by log2e/sqrt(8)
//   [65536, 131072)   QVf16: per j, 8 dwords = q[j] 8 halfs | v[j] 8 halfs
//   [131072, 131328)  bmax[256] per-proj-block max ||q||^2 (plain store)
//   [131328, ...)     partH[nch][9][8192] f16 partials, c-major

#define QV_OFF   65536
#define BMAX_OFF 131072
#define PART_OFF 131328

typedef _Float16 hv2 __attribute__((ext_vector_type(2)));
union HVU { unsigned u; hv2 v; };

static __device__ __forceinline__ unsigned pku(float a, float b) {
    auto t = __builtin_amdgcn_cvt_pkrtz(a, b);
    union { decltype(t) x; unsigned u; } c; c.x = t; return c.u;
}
static __device__ __forceinline__ hv2 asV(unsigned u) { HVU t; t.u = u; return t.v; }

__global__ __launch_bounds__(256) void proj_kernel(
    const float* __restrict__ x,
    const float* __restrict__ Kw, const float* __restrict__ Kb,
    const float* __restrict__ Qw, const float* __restrict__ Qb,
    const float* __restrict__ Vw, const float* __restrict__ Vb,
    float* __restrict__ Xksf32, unsigned* __restrict__ QV,
    float* __restrict__ bmax)
{
    __shared__ float xs[32 * 49];     // +1 pad
    __shared__ float wAll[3 * 388];   // stride 388 (mod 32 = 4) spreads 3 mats
    __shared__ float bs[24];
    __shared__ float outv[32][25];    // 24 cols + pad
    const int tid = threadIdx.x;
    const int r0 = blockIdx.x * 32;

    for (int i = tid; i < 1536; i += 256) {
        int r = i / 48, c = i - r * 48;
        xs[r * 49 + c] = x[r0 * 48 + i];
    }
    for (int i = tid; i < 384; i += 256) {
        wAll[i]       = Kw[i];
        wAll[388 + i] = Qw[i];
        wAll[776 + i] = Vw[i];
    }
    if (tid < 8)       bs[tid] = Kb[tid];
    else if (tid < 16) bs[tid] = Qb[tid - 8];
    else if (tid < 24) bs[tid] = Vb[tid - 16];
    __syncthreads();

    const int rl = tid >> 3;
    const int g  = tid & 7;
    const int c0 = 3 * g;
    const float* xr = &xs[rl * 49];
    const float* w0 = &wAll[((c0 + 0) >> 3) * 388 + ((c0 + 0) & 7)];
    const float* w1 = &wAll[((c0 + 1) >> 3) * 388 + ((c0 + 1) & 7)];
    const float* w2 = &wAll[((c0 + 2) >> 3) * 388 + ((c0 + 2) & 7)];
    float a0 = bs[c0], a1 = bs[c0 + 1], a2 = bs[c0 + 2];
    #pragma unroll
    for (int k = 0; k < 48; k++) {
        const float xv = xr[k];
        a0 = fmaf(xv, w0[k * 8], a0);
        a1 = fmaf(xv, w1[k * 8], a1);
        a2 = fmaf(xv, w2[k * 8], a2);
    }
    outv[rl][c0] = a0; outv[rl][c0 + 1] = a1; outv[rl][c0 + 2] = a2;
    __syncthreads();

    const float kscale = 0.51008732149f;  // (1/sqrt(8)) * log2(e)
    {   // K rows f32, pre-scaled: thread = (row r, col c), coalesced
        const int r = tid >> 3, c = tid & 7;
        Xksf32[(r0 + r) * 8 + c] = outv[r][c] * kscale;
    }
    {   // QV f16: per j 8 dwords (q pairs then v pairs); thread = (j, d)
        const int j = tid >> 3, d = tid & 7;
        const int base = (d < 4) ? (8 + 2 * d) : (16 + 2 * (d - 4));
        QV[(r0 + j) * 8 + d] = pku(outv[j][base], outv[j][base + 1]);
    }
    if (tid >= 192 && tid < 224) {        // block-max ||q||^2 (fp32)
        const int r = tid - 192;
        float n2 = 0.f;
        #pragma unroll
        for (int c = 0; c < 8; c++) n2 = fmaf(outv[r][8 + c], outv[r][8 + c], n2);
        #pragma unroll
        for (int off = 16; off > 0; off >>= 1)
            n2 = fmaxf(n2, __shfl_xor(n2, off, 64));
        if (r == 0) bmax[blockIdx.x] = n2;
    }
}

// grid = 8 row-groups (1024 rows: 4 waves x 64 lanes x 4 rows/lane) x nch.
// Tile staged once as f32 (cvt at staging); hot loop has NO cvt.
__global__ __launch_bounds__(256) void attn_kernel(
    const float* __restrict__ Xksf32, const unsigned* __restrict__ QV,
    const float* __restrict__ bmax,
    __half* __restrict__ partH, int C)
{
    __shared__ float4 tile[512];       // up to 128 j x 64 B f32
    const int tid  = threadIdx.x;
    const int lane = tid & 63;
    const int wv   = tid >> 6;
    const int g    = blockIdx.x & 7;
    const int ch   = blockIdx.x >> 3;

    // stage chunk tile f16 -> f32 once (block-cooperative; 2 cvt/thread)
    {
        const unsigned* src = QV + (size_t)ch * C * 8;
        float2* t2 = (float2*)tile;
        for (int t = tid; t < C * 8; t += 256) {
            const hv2 h = asV(src[t]);
            const int j = t >> 3, k = t & 7;
            const int slot = (k < 4) ? (2 * k) : (8 + 2 * (k - 4));  // even
            float2 w; w.x = (float)h.x; w.y = (float)h.y;
            t2[(j * 16 + slot) >> 1] = w;
        }
    }

    // qmax2 = max over 256 per-proj-block maxima
    float m = fmaxf(fmaxf(bmax[lane], bmax[64 + lane]),
                    fmaxf(bmax[128 + lane], bmax[192 + lane]));
    #pragma unroll
    for (int off = 32; off > 0; off >>= 1)
        m = fmaxf(m, __shfl_xor(m, off, 64));
    const float qmax2 = m;

    const int rbase = g * 1024 + wv * 256 + lane;   // rows: rbase + 64k
    float kf[4][8], sinit[4], l[4], acc[4][8];
    const float4* Xk4 = (const float4*)Xksf32;
    #pragma unroll
    for (int k = 0; k < 4; k++) {
        const int row = rbase + 64 * k;             // coalesced per k
        const float4 ka = Xk4[row * 2], kb = Xk4[row * 2 + 1];
        kf[k][0] = ka.x; kf[k][1] = ka.y; kf[k][2] = ka.z; kf[k][3] = ka.w;
        kf[k][4] = kb.x; kf[k][5] = kb.y; kf[k][6] = kb.z; kf[k][7] = kb.w;
        float kn2 = 0.f;
        #pragma unroll
        for (int c = 0; c < 8; c++) kn2 = fmaf(kf[k][c], kf[k][c], kn2);
        sinit[k] = -sqrtf(kn2 * qmax2);  // s <= -sinit: p in (0,~1]
        l[k] = 0.f;
        #pragma unroll
        for (int c = 0; c < 8; c++) acc[k][c] = 0.f;
    }

    __syncthreads();                   // tile ready; no further barriers

    #pragma unroll 4
    for (int j = 0; j < C; j++) {
        // wave-uniform ds_read_b128 x4: broadcast, in-order, pipelined
        const float4 q0 = tile[j * 4 + 0];   // q[0..3]
        const float4 q1 = tile[j * 4 + 1];   // q[4..7]
        const float4 v0 = tile[j * 4 + 2];   // v[0..3]
        const float4 v1 = tile[j * 4 + 3];   // v[4..7]
        #pragma unroll
        for (int k = 0; k < 4; k++) {
            float s = sinit[k];
            s = fmaf(kf[k][0], q0.x, s); s = fmaf(kf[k][1], q0.y, s);
            s = fmaf(kf[k][2], q0.z, s); s = fmaf(kf[k][3], q0.w, s);
            s = fmaf(kf[k][4], q1.x, s); s = fmaf(kf[k][5], q1.y, s);
            s = fmaf(kf[k][6], q1.z, s); s = fmaf(kf[k][7], q1.w, s);
            const float p = __builtin_amdgcn_exp2f(s);
            l[k] += p;
            acc[k][0] = fmaf(p, v0.x, acc[k][0]);
            acc[k][1] = fmaf(p, v0.y, acc[k][1]);
            acc[k][2] = fmaf(p, v0.z, acc[k][2]);
            acc[k][3] = fmaf(p, v0.w, acc[k][3]);
            acc[k][4] = fmaf(p, v1.x, acc[k][4]);
            acc[k][5] = fmaf(p, v1.y, acc[k][5]);
            acc[k][6] = fmaf(p, v1.z, acc[k][6]);
            acc[k][7] = fmaf(p, v1.w, acc[k][7]);
        }
    }

    // c-major f16 partial store: lanes = consecutive rows (coalesced)
    #pragma unroll
    for (int k = 0; k < 4; k++) {
        const int row = rbase + 64 * k;
        #pragma unroll
        for (int c = 0; c < 8; c++)
            partH[((size_t)(ch * 9 + c) << 13) + row] = __float2half_rn(acc[k][c]);
        partH[((size_t)(ch * 9 + 8) << 13) + row] = __float2half_rn(l[k]);
    }
}

// grid = 128 blocks x 64 rows; thread (r = tid&63, slice-group s = tid>>6)
__global__ __launch_bounds__(256) void finish_kernel(
    const float* __restrict__ x,
    const float* __restrict__ Zw, const float* __restrict__ Zb,
    const __half* __restrict__ partH, float* __restrict__ out, int nch)
{
    __shared__ float red[4][64][10];
    __shared__ float Zs[64][9];
    __shared__ float zw_s[384];
    __shared__ float zb_s[48];
    const int tid = threadIdx.x;
    const int r0 = blockIdx.x * 64;

    for (int i = tid; i < 384; i += 256) zw_s[i] = Zw[i];
    if (tid < 48) zb_s[tid] = Zb[tid];

    const int r = tid & 63, s = tid >> 6;
    const int row = r0 + r;
    const int cps = nch >> 2;
    float a[9];
    #pragma unroll
    for (int c = 0; c < 9; c++) a[c] = 0.f;
    for (int i = 0; i < cps; i++) {
        const int ch = s * cps + i;
        const __half* p = partH + ((size_t)(ch * 9) << 13) + row;
        #pragma unroll
        for (int c = 0; c < 9; c++) a[c] += __half2float(p[(size_t)c << 13]);
    }
    #pragma unroll
    for (int c = 0; c < 9; c++) red[s][r][c] = a[c];
    __syncthreads();
    if (tid < 64) {
        float b[9];
        #pragma unroll
        for (int c = 0; c < 9; c++)
            b[c] = red[0][tid][c] + red[1][tid][c] + red[2][tid][c] + red[3][tid][c];
        const float inv = 1.0f / b[8];
        #pragma unroll
        for (int c = 0; c < 8; c++) Zs[tid][c] = b[c] * inv;
    }
    __syncthreads();

    for (int e = tid; e < 64 * 48; e += 256) {
        const int rr = e / 48, c = e - rr * 48;
        float o = x[r0 * 48 + e] + zb_s[c];
        #pragma unroll
        for (int k = 0; k < 8; k++) o = fmaf(Zs[rr][k], zw_s[k * 48 + c], o);
        out[r0 * 48 + e] = o;
    }
}

extern "C" void kernel_launch(void* const* d_in, const int* in_sizes, int n_in,
                              void* d_out, int out_size, void* d_ws, size_t ws_size,
                              hipStream_t stream) {
    const float* x  = (const float*)d_in[0];
    const float* Kw = (const float*)d_in[1];
    const float* Kb = (const float*)d_in[2];
    const float* Qw = (const float*)d_in[3];
    const float* Qb = (const float*)d_in[4];
    const float* Vw = (const float*)d_in[5];
    const float* Vb = (const float*)d_in[6];
    const float* Zw = (const float*)d_in[7];
    const float* Zb = (const float*)d_in[8];
    float* out = (float*)d_out;

    float* ws = (float*)d_ws;
    float* Xksf32 = ws;
    unsigned* QV  = (unsigned*)(ws + QV_OFF);
    float* bmax   = ws + BMAX_OFF;
    __half* partH = (__half*)(ws + PART_OFF);

    // largest chunk count whose f16 partials fit (tile cap: C <= 128 j)
    int nch = 128;
    while (nch > 64 &&
           (size_t)PART_OFF * 4 + (size_t)nch * 9 * 8192 * 2 > ws_size) nch >>= 1;
    const int C = 8192 / nch;   // j's per chunk (64 when nch=128)

    proj_kernel<<<256, 256, 0, stream>>>(x, Kw, Kb, Qw, Qb, Vw, Vb,
                                         Xksf32, QV, bmax);
    attn_kernel<<<8 * nch, 256, 0, stream>>>(Xksf32, QV, bmax, partH, C);
    finish_kernel<<<128, 256, 0, stream>>>(x, Zw, Zb, partH, out, nch);
}